// Round 5
// baseline (131.483 us; speedup 1.0000x reference)
//
#include <hip/hip_runtime.h>

#define NROWS 8192
#define NSPLIT 8
#define JT (NROWS / NSPLIT)  // 1024 j's per split
#define NITER (JT / 64)      // 16
#define L2E 1.4426950408889634f

typedef __attribute__((ext_vector_type(4))) float f32x4;
typedef __attribute__((ext_vector_type(8))) __bf16 bf16x8;
typedef __attribute__((ext_vector_type(4))) unsigned int u32x4;

__device__ __forceinline__ unsigned short f2bf(float x) {
  unsigned u = __float_as_uint(x);
  u += 0x7fffu + ((u >> 16) & 1u);
  return (unsigned short)(u >> 16);
}

// ---------------------------------------------------------------------------
// Kernel A: Wh = h@W (stored bf16 in MFMA-B-fragment order), src=Wh@a1, dst=Wh@a2
// src/dst pre-scaled by log2(e) so downstream works in exp2 domain.
// Fragment layout: slot (jc, nt, lane, e) holds Wh[j = 32*jc + 8*(lane>>4) + e][nt*16 + (lane&15)]
// ---------------------------------------------------------------------------
__global__ __launch_bounds__(256) void k_prep(
    const float* __restrict__ h, const float* __restrict__ W,
    const float* __restrict__ a, unsigned short* __restrict__ WhB,
    float* __restrict__ src, float* __restrict__ dst) {
  int i = blockIdx.x * 4 + (threadIdx.x >> 6);  // row
  int lane = threadIdx.x & 63;                  // feature
  const float* hrow = h + (size_t)i * 256;
  float s = 0.f;
#pragma unroll 4
  for (int k = 0; k < 256; k += 4) {
    float4 hv = *(const float4*)(hrow + k);
    s = fmaf(hv.x, W[(k + 0) * 64 + lane], s);
    s = fmaf(hv.y, W[(k + 1) * 64 + lane], s);
    s = fmaf(hv.z, W[(k + 2) * 64 + lane], s);
    s = fmaf(hv.w, W[(k + 3) * 64 + lane], s);
  }
  int nt = lane >> 4, c = lane & 15;
  int gi = (i >> 3) & 3, e = i & 7;
  int idx = ((((i >> 5) * 4 + nt) * 64) + c + 16 * gi) * 8 + e;
  WhB[idx] = f2bf(s);
  float v1 = s * a[lane];
  float v2 = s * a[64 + lane];
#pragma unroll
  for (int d = 32; d; d >>= 1) {
    v1 += __shfl_xor(v1, d);
    v2 += __shfl_xor(v2, d);
  }
  if (lane == 0) {
    src[i] = v1 * L2E;
    dst[i] = v2 * L2E;
  }
}

// ---------------------------------------------------------------------------
// Kernel A2: dmax = max_j dst[j]  (global scalar; 1 block)
// ---------------------------------------------------------------------------
__global__ __launch_bounds__(256) void k_dmax(
    const float* __restrict__ dst, float* __restrict__ dmax) {
  __shared__ float red[4];
  float v = -INFINITY;
  for (int i = threadIdx.x; i < NROWS; i += 256) v = fmaxf(v, dst[i]);
#pragma unroll
  for (int d = 32; d; d >>= 1) v = fmaxf(v, __shfl_xor(v, d));
  if ((threadIdx.x & 63) == 0) red[threadIdx.x >> 6] = v;
  __syncthreads();
  if (threadIdx.x == 0)
    *dmax = fmaxf(fmaxf(red[0], red[1]), fmaxf(red[2], red[3]));
}

// ---------------------------------------------------------------------------
// Kernel P: pack adj to 1 bit per entry. One wave per row; lanes read
// CONSECUTIVE ints (256 B contiguous per instruction = pure streaming),
// ballot -> 64-bit mask per 64 columns (bit e = col base+e), coalesced
// 512 B stores. This kernel carries the unavoidable 268 MB adj read at
// stream rate instead of k_attn's 16-way line scatter.
// ---------------------------------------------------------------------------
__global__ __launch_bounds__(256) void k_pack(
    const int* __restrict__ adj, unsigned long long* __restrict__ packed) {
  int row = blockIdx.x * 4 + (threadIdx.x >> 6);
  int lane = threadIdx.x & 63;
  const int* rp = adj + (size_t)row * NROWS;
#pragma unroll
  for (int half = 0; half < 2; ++half) {
    unsigned long long word = 0;
#pragma unroll 8
    for (int it = 0; it < 64; ++it) {
      int v = rp[half * 4096 + it * 64 + lane];
      unsigned long long bal = __ballot(v > 0);
      word = (lane == it) ? bal : word;
    }
    packed[(size_t)row * 128 + half * 64 + lane] = word;
  }
}

// ---------------------------------------------------------------------------
// Kernel B: fused masked-softmax + PV, split along j into NSPLIT partials.
// One wave = one (16-row M-tile, split) task. Absolute bound
// Mi = lrelu(src_i + dmax) >= all scores of row i => P = 2^(ev-Mi) <= 1:
// no online max, no rescale, no cross-lane ops in the loop.
// adj comes from the packed bitmask: ONE 8-byte load per lane per iter
// (L2-resident 8 MB) instead of 4 KB of scattered HBM traffic.
// ---------------------------------------------------------------------------
__global__ __launch_bounds__(256, 4) void k_attn(
    const unsigned long long* __restrict__ packed,
    const unsigned short* __restrict__ WhB,
    const float* __restrict__ src, const float* __restrict__ dst,
    const float* __restrict__ dmax,
    float* __restrict__ pl, float* __restrict__ pacc) {
  __shared__ float ldst[JT];
  int task = blockIdx.x * 4 + (threadIdx.x >> 6);  // 0 .. 512*NSPLIT-1
  int sp = task >> 9;                              // split (same for whole block)
  int mt = task & 511;                             // M-tile index
  int lane = threadIdx.x & 63;
  int r = lane & 15;  // row within tile / C col
  int g = lane >> 4;  // k-slot group
  int row0 = mt * 16;
  int jbase = sp * JT;

  // stage this split's dst slice to LDS (block-shared)
  for (int k = threadIdx.x; k < JT; k += 256) ldst[k] = dst[jbase + k];
  __syncthreads();

  float srcr = src[row0 + r];
  float vB = srcr + *dmax;
  float Mi = fmaxf(vB, 0.2f * vB);  // upper bound on this row's scores

  float lrow = 0.f;
  f32x4 acc[4] = {f32x4{0.f, 0.f, 0.f, 0.f}, f32x4{0.f, 0.f, 0.f, 0.f},
                  f32x4{0.f, 0.f, 0.f, 0.f}, f32x4{0.f, 0.f, 0.f, 0.f}};
  const unsigned long long* pwp =
      packed + (size_t)(row0 + r) * (NROWS / 64) + (jbase >> 6);
  const bf16x8* Bfr = (const bf16x8*)WhB;

#pragma unroll
  for (int it = 0; it < NITER; ++it) {
    const int jb = it * 64;

    // packed adj word for this lane's row, cols [jbase+jb, +64)
    unsigned long long pw = pwp[it];

    // B(t): L2-hot fragment loads
    int jc = (jbase + jb) >> 5;
    const bf16x8* bp = Bfr + (size_t)jc * 256 + lane;
    bf16x8 b0 = bp[0];
    bf16x8 b1 = bp[64];
    bf16x8 b2 = bp[128];
    bf16x8 b3 = bp[192];
    bf16x8 b4 = bp[256];
    bf16x8 b5 = bp[320];
    bf16x8 b6 = bp[384];
    bf16x8 b7 = bp[448];

    // dst from LDS (4 addresses per wave -> broadcast, conflict-free)
    const float* dl = ldst + jb + 8 * g;
    float4 d0 = *(const float4*)(dl);
    float4 d1 = *(const float4*)(dl + 4);
    float4 d2 = *(const float4*)(dl + 32);
    float4 d3 = *(const float4*)(dl + 36);

    // bits for cols jb+8g+e (lo) and jb+32+8g+e (hi), e = bit index 0..7
    unsigned lo = (unsigned)(pw >> (8 * g));
    unsigned hi = (unsigned)(pw >> (32 + 8 * g));

    float p[16];
#define PE(P, BIT, DD)                    \
  {                                       \
    float v_ = srcr + (DD);               \
    v_ = fmaxf(v_, 0.2f * v_);            \
    float e_ = exp2f(v_ - Mi);            \
    (P) = (BIT) ? e_ : 0.f;               \
  }
    PE(p[0], lo & 1u, d0.x)   PE(p[1], lo & 2u, d0.y)
    PE(p[2], lo & 4u, d0.z)   PE(p[3], lo & 8u, d0.w)
    PE(p[4], lo & 16u, d1.x)  PE(p[5], lo & 32u, d1.y)
    PE(p[6], lo & 64u, d1.z)  PE(p[7], lo & 128u, d1.w)
    PE(p[8], hi & 1u, d2.x)   PE(p[9], hi & 2u, d2.y)
    PE(p[10], hi & 4u, d2.z)  PE(p[11], hi & 8u, d2.w)
    PE(p[12], hi & 16u, d3.x) PE(p[13], hi & 32u, d3.y)
    PE(p[14], hi & 64u, d3.z) PE(p[15], hi & 128u, d3.w)
#undef PE

    unsigned q[8];
#pragma unroll
    for (int t = 0; t < 16; t += 2) {
      lrow += p[t] + p[t + 1];
      unsigned qq;
      asm("v_cvt_pk_bf16_f32 %0, %1, %2" : "=v"(qq) : "v"(p[t]), "v"(p[t + 1]));
      q[t >> 1] = qq;
    }
    u32x4 qv0 = {q[0], q[1], q[2], q[3]};
    u32x4 qv1 = {q[4], q[5], q[6], q[7]};
    bf16x8 A0 = __builtin_bit_cast(bf16x8, qv0);
    bf16x8 A1 = __builtin_bit_cast(bf16x8, qv1);

    __builtin_amdgcn_s_setprio(1);
    acc[0] = __builtin_amdgcn_mfma_f32_16x16x32_bf16(A0, b0, acc[0], 0, 0, 0);
    acc[1] = __builtin_amdgcn_mfma_f32_16x16x32_bf16(A0, b1, acc[1], 0, 0, 0);
    acc[2] = __builtin_amdgcn_mfma_f32_16x16x32_bf16(A0, b2, acc[2], 0, 0, 0);
    acc[3] = __builtin_amdgcn_mfma_f32_16x16x32_bf16(A0, b3, acc[3], 0, 0, 0);
    acc[0] = __builtin_amdgcn_mfma_f32_16x16x32_bf16(A1, b4, acc[0], 0, 0, 0);
    acc[1] = __builtin_amdgcn_mfma_f32_16x16x32_bf16(A1, b5, acc[1], 0, 0, 0);
    acc[2] = __builtin_amdgcn_mfma_f32_16x16x32_bf16(A1, b6, acc[2], 0, 0, 0);
    acc[3] = __builtin_amdgcn_mfma_f32_16x16x32_bf16(A1, b7, acc[3], 0, 0, 0);
    __builtin_amdgcn_s_setprio(0);
  }

  // row-sum of l across the 4 g-groups (lanes r, r+16, r+32, r+48)
  lrow += __shfl_xor(lrow, 16);
  lrow += __shfl_xor(lrow, 32);
  if (lane < 16) pl[sp * NROWS + row0 + lane] = lrow;
#pragma unroll
  for (int nt = 0; nt < 4; nt++)
#pragma unroll
    for (int q2 = 0; q2 < 4; q2++)
      pacc[((size_t)sp * NROWS + row0 + 4 * g + q2) * 64 + nt * 16 + r] = acc[nt][q2];
}

// ---------------------------------------------------------------------------
// Kernel C: combine = plain sums (all splits share the same reference Mi).
// ---------------------------------------------------------------------------
__global__ __launch_bounds__(256) void k_comb(
    const float* __restrict__ pl, const float* __restrict__ pacc,
    float* __restrict__ out) {
  int t = blockIdx.x * 256 + threadIdx.x;
  int row = t >> 6, f = t & 63;
  float L = 0.f, o = 0.f;
#pragma unroll
  for (int s2 = 0; s2 < NSPLIT; s2++) {
    L += pl[s2 * NROWS + row];
    o += pacc[((size_t)s2 * NROWS + row) * 64 + f];
  }
  out[t] = o / L;
}

extern "C" void kernel_launch(void* const* d_in, const int* in_sizes, int n_in,
                              void* d_out, int out_size, void* d_ws, size_t ws_size,
                              hipStream_t stream) {
  const float* h = (const float*)d_in[0];
  const float* W = (const float*)d_in[1];
  const float* a = (const float*)d_in[2];
  const int* adj = (const int*)d_in[3];
  float* out = (float*)d_out;

  char* ws = (char*)d_ws;
  unsigned short* WhB = (unsigned short*)ws;                 // 1 MB
  float* src = (float*)(ws + 0x100000);                      // 32 KB
  float* dst = (float*)(ws + 0x108000);                      // 32 KB
  float* dmax = (float*)(ws + 0x110000);                     // 256 B
  float* pl = (float*)(ws + 0x110100);                       // 256 KB
  float* pacc = (float*)(ws + 0x150100);                     // 16 MB
  unsigned long long* packed = (unsigned long long*)(ws + 0x1150100);  // 8 MB

  hipLaunchKernelGGL(k_prep, dim3(NROWS / 4), dim3(256), 0, stream, h, W, a, WhB, src, dst);
  hipLaunchKernelGGL(k_dmax, dim3(1), dim3(256), 0, stream, dst, dmax);
  hipLaunchKernelGGL(k_pack, dim3(NROWS / 4), dim3(256), 0, stream, adj, packed);
  hipLaunchKernelGGL(k_attn, dim3(512 * NSPLIT / 4), dim3(256), 0, stream,
                     packed, WhB, src, dst, dmax, pl, pacc);
  hipLaunchKernelGGL(k_comb, dim3(NROWS * 64 / 256), dim3(256), 0, stream, pl, pacc, out);
}

// Round 7
// 118.312 us; speedup vs baseline: 1.1113x; 1.1113x over previous
//
#include <hip/hip_runtime.h>

#define NROWS 8192
#define NSPLIT 8
#define JT (NROWS / NSPLIT)  // 1024 j's per split
#define NITER (JT / 64)      // 16
#define L2E 1.4426950408889634f

typedef __attribute__((ext_vector_type(4))) float f32x4;
typedef __attribute__((ext_vector_type(8))) __bf16 bf16x8;
typedef __attribute__((ext_vector_type(4))) unsigned int u32x4;

__device__ __forceinline__ unsigned short f2bf(float x) {
  unsigned u = __float_as_uint(x);
  u += 0x7fffu + ((u >> 16) & 1u);
  return (unsigned short)(u >> 16);
}

// ---------------------------------------------------------------------------
// Kernel A: Wh = h@W (stored bf16 in MFMA-B-fragment order), src=Wh@a1, dst=Wh@a2
// src/dst pre-scaled by log2(e) so downstream works in exp2 domain.
// Fragment layout: slot (jc, nt, lane, e) holds Wh[j = 32*jc + 8*(lane>>4) + e][nt*16 + (lane&15)]
// ---------------------------------------------------------------------------
__global__ __launch_bounds__(256) void k_prep(
    const float* __restrict__ h, const float* __restrict__ W,
    const float* __restrict__ a, unsigned short* __restrict__ WhB,
    float* __restrict__ src, float* __restrict__ dst) {
  int i = blockIdx.x * 4 + (threadIdx.x >> 6);  // row
  int lane = threadIdx.x & 63;                  // feature
  const float* hrow = h + (size_t)i * 256;
  float s = 0.f;
#pragma unroll 4
  for (int k = 0; k < 256; k += 4) {
    float4 hv = *(const float4*)(hrow + k);
    s = fmaf(hv.x, W[(k + 0) * 64 + lane], s);
    s = fmaf(hv.y, W[(k + 1) * 64 + lane], s);
    s = fmaf(hv.z, W[(k + 2) * 64 + lane], s);
    s = fmaf(hv.w, W[(k + 3) * 64 + lane], s);
  }
  int nt = lane >> 4, c = lane & 15;
  int gi = (i >> 3) & 3, e = i & 7;
  int idx = ((((i >> 5) * 4 + nt) * 64) + c + 16 * gi) * 8 + e;
  WhB[idx] = f2bf(s);
  float v1 = s * a[lane];
  float v2 = s * a[64 + lane];
#pragma unroll
  for (int d = 32; d; d >>= 1) {
    v1 += __shfl_xor(v1, d);
    v2 += __shfl_xor(v2, d);
  }
  if (lane == 0) {
    src[i] = v1 * L2E;
    dst[i] = v2 * L2E;
  }
}

// ---------------------------------------------------------------------------
// Kernel A2: dmax = max_j dst[j]  (global scalar; 1 block)
// ---------------------------------------------------------------------------
__global__ __launch_bounds__(256) void k_dmax(
    const float* __restrict__ dst, float* __restrict__ dmax) {
  __shared__ float red[4];
  float v = -INFINITY;
  for (int i = threadIdx.x; i < NROWS; i += 256) v = fmaxf(v, dst[i]);
#pragma unroll
  for (int d = 32; d; d >>= 1) v = fmaxf(v, __shfl_xor(v, d));
  if ((threadIdx.x & 63) == 0) red[threadIdx.x >> 6] = v;
  __syncthreads();
  if (threadIdx.x == 0)
    *dmax = fmaxf(fmaxf(red[0], red[1]), fmaxf(red[2], red[3]));
}

// ---------------------------------------------------------------------------
// Kernel B (FUSED): in-wave ballot-pack of adj + masked-softmax + PV.
// One wave = one (16-row M-tile, split) task.
//
// Phase 1: wave reads its 16x1024 adj region with CONSECUTIVE-lane ints
// (256 B/instr streaming), ballots -> wave-uniform u64 mask per
// (row, 64-col chunk); mask(r, ch) parked in reg mk[ch>>2] of lane
// 16*(ch&3)+r (bijective; 4 u64/lane hold all 256 masks). adj touched
// exactly once, fully coalesced, no intermediate buffer.
//
// Phase 2: per 64-col iter, ONE __shfl fetches this lane's mask; bits gate
// exp2(lrelu(src+dst) - Mi) with the absolute bound Mi = lrelu(src_i+dmax)
// (no online max / rescale). bf16 P x Wh via 8 MFMA per iter.
// ---------------------------------------------------------------------------
__global__ __launch_bounds__(256, 4) void k_attn(
    const int* __restrict__ adj, const unsigned short* __restrict__ WhB,
    const float* __restrict__ src, const float* __restrict__ dst,
    const float* __restrict__ dmax,
    float* __restrict__ pl, float* __restrict__ pacc) {
  __shared__ float ldst[JT];
  int task = blockIdx.x * 4 + (threadIdx.x >> 6);  // 0 .. 512*NSPLIT-1
  int sp = task >> 9;                              // split (same for whole block)
  int mt = task & 511;                             // M-tile index
  int lane = threadIdx.x & 63;
  int r = lane & 15;  // row within tile / C col
  int g = lane >> 4;  // k-slot group
  int row0 = mt * 16;
  int jbase = sp * JT;

  // stage this split's dst slice to LDS (block-shared)
  for (int k = threadIdx.x; k < JT; k += 256) ldst[k] = dst[jbase + k];
  __syncthreads();

  // ---- Phase 1: ballot-pack 16 rows x 1024 cols into 4 u64 regs/lane ----
  unsigned long long mk0 = 0, mk1 = 0, mk2 = 0, mk3 = 0;
  {
    const int* abase = adj + (size_t)row0 * NROWS + jbase + lane;
#pragma unroll
    for (int rr = 0; rr < 16; ++rr) {
      const int* rp = abase + (size_t)rr * NROWS;
#pragma unroll
      for (int ch = 0; ch < 16; ++ch) {
        int v = rp[ch * 64];
        unsigned long long bal = __ballot(v > 0);
        const int holder = ((ch & 3) << 4) + rr;
        if ((ch >> 2) == 0) mk0 = (lane == holder) ? bal : mk0;
        if ((ch >> 2) == 1) mk1 = (lane == holder) ? bal : mk1;
        if ((ch >> 2) == 2) mk2 = (lane == holder) ? bal : mk2;
        if ((ch >> 2) == 3) mk3 = (lane == holder) ? bal : mk3;
      }
    }
  }

  float srcr = src[row0 + r];
  float vB = srcr + *dmax;
  float Mi = fmaxf(vB, 0.2f * vB);  // upper bound on this row's scores

  float lrow = 0.f;
  f32x4 acc[4] = {f32x4{0.f, 0.f, 0.f, 0.f}, f32x4{0.f, 0.f, 0.f, 0.f},
                  f32x4{0.f, 0.f, 0.f, 0.f}, f32x4{0.f, 0.f, 0.f, 0.f}};
  const bf16x8* Bfr = (const bf16x8*)WhB;

  // ---- Phase 2: bitmask softmax + PV ----
#pragma unroll
  for (int it = 0; it < NITER; ++it) {
    const int jb = it * 64;

    // mask(r, it): one cross-lane fetch, replaces any adj memory access
    unsigned long long pw;
    if ((it >> 2) == 0) pw = __shfl(mk0, ((it & 3) << 4) + r);
    if ((it >> 2) == 1) pw = __shfl(mk1, ((it & 3) << 4) + r);
    if ((it >> 2) == 2) pw = __shfl(mk2, ((it & 3) << 4) + r);
    if ((it >> 2) == 3) pw = __shfl(mk3, ((it & 3) << 4) + r);

    // B(t): L2-hot fragment loads (1 KB coalesced per instr)
    int jc = (jbase + jb) >> 5;
    const bf16x8* bp = Bfr + (size_t)jc * 256 + lane;
    bf16x8 b0 = bp[0];
    bf16x8 b1 = bp[64];
    bf16x8 b2 = bp[128];
    bf16x8 b3 = bp[192];
    bf16x8 b4 = bp[256];
    bf16x8 b5 = bp[320];
    bf16x8 b6 = bp[384];
    bf16x8 b7 = bp[448];

    // dst from LDS (4 addresses per wave -> broadcast, conflict-free)
    const float* dl = ldst + jb + 8 * g;
    float4 d0 = *(const float4*)(dl);
    float4 d1 = *(const float4*)(dl + 4);
    float4 d2 = *(const float4*)(dl + 32);
    float4 d3 = *(const float4*)(dl + 36);

    // bits for cols jb+8g+e (lo) and jb+32+8g+e (hi), e = bit index 0..7
    unsigned lo = (unsigned)(pw >> (8 * g));
    unsigned hi = (unsigned)(pw >> (32 + 8 * g));

    float p[16];
#define PE(P, BIT, DD)                    \
  {                                       \
    float v_ = srcr + (DD);               \
    v_ = fmaxf(v_, 0.2f * v_);            \
    float e_ = exp2f(v_ - Mi);            \
    (P) = (BIT) ? e_ : 0.f;               \
  }
    PE(p[0], lo & 1u, d0.x)   PE(p[1], lo & 2u, d0.y)
    PE(p[2], lo & 4u, d0.z)   PE(p[3], lo & 8u, d0.w)
    PE(p[4], lo & 16u, d1.x)  PE(p[5], lo & 32u, d1.y)
    PE(p[6], lo & 64u, d1.z)  PE(p[7], lo & 128u, d1.w)
    PE(p[8], hi & 1u, d2.x)   PE(p[9], hi & 2u, d2.y)
    PE(p[10], hi & 4u, d2.z)  PE(p[11], hi & 8u, d2.w)
    PE(p[12], hi & 16u, d3.x) PE(p[13], hi & 32u, d3.y)
    PE(p[14], hi & 64u, d3.z) PE(p[15], hi & 128u, d3.w)
#undef PE

    unsigned q[8];
#pragma unroll
    for (int t = 0; t < 16; t += 2) {
      lrow += p[t] + p[t + 1];
      unsigned qq;
      asm("v_cvt_pk_bf16_f32 %0, %1, %2" : "=v"(qq) : "v"(p[t]), "v"(p[t + 1]));
      q[t >> 1] = qq;
    }
    u32x4 qv0 = {q[0], q[1], q[2], q[3]};
    u32x4 qv1 = {q[4], q[5], q[6], q[7]};
    bf16x8 A0 = __builtin_bit_cast(bf16x8, qv0);
    bf16x8 A1 = __builtin_bit_cast(bf16x8, qv1);

    __builtin_amdgcn_s_setprio(1);
    acc[0] = __builtin_amdgcn_mfma_f32_16x16x32_bf16(A0, b0, acc[0], 0, 0, 0);
    acc[1] = __builtin_amdgcn_mfma_f32_16x16x32_bf16(A0, b1, acc[1], 0, 0, 0);
    acc[2] = __builtin_amdgcn_mfma_f32_16x16x32_bf16(A0, b2, acc[2], 0, 0, 0);
    acc[3] = __builtin_amdgcn_mfma_f32_16x16x32_bf16(A0, b3, acc[3], 0, 0, 0);
    acc[0] = __builtin_amdgcn_mfma_f32_16x16x32_bf16(A1, b4, acc[0], 0, 0, 0);
    acc[1] = __builtin_amdgcn_mfma_f32_16x16x32_bf16(A1, b5, acc[1], 0, 0, 0);
    acc[2] = __builtin_amdgcn_mfma_f32_16x16x32_bf16(A1, b6, acc[2], 0, 0, 0);
    acc[3] = __builtin_amdgcn_mfma_f32_16x16x32_bf16(A1, b7, acc[3], 0, 0, 0);
    __builtin_amdgcn_s_setprio(0);
  }

  // row-sum of l across the 4 g-groups (lanes r, r+16, r+32, r+48)
  lrow += __shfl_xor(lrow, 16);
  lrow += __shfl_xor(lrow, 32);
  if (lane < 16) pl[sp * NROWS + row0 + lane] = lrow;
#pragma unroll
  for (int nt = 0; nt < 4; nt++)
#pragma unroll
    for (int q2 = 0; q2 < 4; q2++)
      pacc[((size_t)sp * NROWS + row0 + 4 * g + q2) * 64 + nt * 16 + r] = acc[nt][q2];
}

// ---------------------------------------------------------------------------
// Kernel C: combine = plain sums (all splits share the same reference Mi).
// ---------------------------------------------------------------------------
__global__ __launch_bounds__(256) void k_comb(
    const float* __restrict__ pl, const float* __restrict__ pacc,
    float* __restrict__ out) {
  int t = blockIdx.x * 256 + threadIdx.x;
  int row = t >> 6, f = t & 63;
  float L = 0.f, o = 0.f;
#pragma unroll
  for (int s2 = 0; s2 < NSPLIT; s2++) {
    L += pl[s2 * NROWS + row];
    o += pacc[((size_t)s2 * NROWS + row) * 64 + f];
  }
  out[t] = o / L;
}

extern "C" void kernel_launch(void* const* d_in, const int* in_sizes, int n_in,
                              void* d_out, int out_size, void* d_ws, size_t ws_size,
                              hipStream_t stream) {
  const float* h = (const float*)d_in[0];
  const float* W = (const float*)d_in[1];
  const float* a = (const float*)d_in[2];
  const int* adj = (const int*)d_in[3];
  float* out = (float*)d_out;

  char* ws = (char*)d_ws;
  unsigned short* WhB = (unsigned short*)ws;           // 1 MB
  float* src = (float*)(ws + 0x100000);                // 32 KB
  float* dst = (float*)(ws + 0x108000);                // 32 KB
  float* dmax = (float*)(ws + 0x110000);               // 256 B
  float* pl = (float*)(ws + 0x110100);                 // 256 KB
  float* pacc = (float*)(ws + 0x150100);               // 16 MB

  hipLaunchKernelGGL(k_prep, dim3(NROWS / 4), dim3(256), 0, stream, h, W, a, WhB, src, dst);
  hipLaunchKernelGGL(k_dmax, dim3(1), dim3(256), 0, stream, dst, dmax);
  hipLaunchKernelGGL(k_attn, dim3(512 * NSPLIT / 4), dim3(256), 0, stream,
                     adj, WhB, src, dst, dmax, pl, pacc);
  hipLaunchKernelGGL(k_comb, dim3(NROWS * 64 / 256), dim3(256), 0, stream, pl, pacc, out);
}